// Round 2
// baseline (931.422 us; speedup 1.0000x reference)
//
#include <hip/hip_runtime.h>
#include <math.h>

#define B 2048
#define C 1024
#define NBLK 256   // persistent-kernel grid; == CU count, all blocks co-resident

typedef _Float16 v2h __attribute__((ext_vector_type(2)));

// ---------------------------------------------------------------------------
// Kernel 1: row softmax of y/2 for both inputs -> fp16 output.
// ---------------------------------------------------------------------------
__global__ __launch_bounds__(256) void softmax_k(const float* __restrict__ ys,
                                                 const float* __restrict__ yt,
                                                 _Float16* __restrict__ ps,
                                                 _Float16* __restrict__ pt) {
    int b = blockIdx.x;
    const float* in;
    _Float16* out;
    if (b < B) { in = ys + (size_t)b * C;        out = ps + (size_t)b * C; }
    else       { in = yt + (size_t)(b - B) * C;  out = pt + (size_t)(b - B) * C; }
    int tid = threadIdx.x;
    int lane = tid & 63, wave = tid >> 6;

    float4 v = reinterpret_cast<const float4*>(in)[tid];
    v.x *= 0.5f; v.y *= 0.5f; v.z *= 0.5f; v.w *= 0.5f;

    float mx = fmaxf(fmaxf(v.x, v.y), fmaxf(v.z, v.w));
    #pragma unroll
    for (int m = 32; m >= 1; m >>= 1) mx = fmaxf(mx, __shfl_xor(mx, m, 64));
    __shared__ float redm[4];
    if (lane == 0) redm[wave] = mx;
    __syncthreads();
    mx = fmaxf(fmaxf(redm[0], redm[1]), fmaxf(redm[2], redm[3]));

    float4 e;
    e.x = expf(v.x - mx); e.y = expf(v.y - mx);
    e.z = expf(v.z - mx); e.w = expf(v.w - mx);
    float s = e.x + e.y + e.z + e.w;
    #pragma unroll
    for (int m = 32; m >= 1; m >>= 1) s += __shfl_xor(s, m, 64);
    __shared__ float reds[4];
    if (lane == 0) reds[wave] = s;
    __syncthreads();
    s = reds[0] + reds[1] + reds[2] + reds[3];

    float inv = 1.0f / s;
    float2 st;
    v2h* sp = (v2h*)&st;
    sp[0] = (v2h){(_Float16)(e.x * inv), (_Float16)(e.y * inv)};
    sp[1] = (v2h){(_Float16)(e.z * inv), (_Float16)(e.w * inv)};
    reinterpret_cast<float2*>(out)[tid] = st;
}

// ---------------------------------------------------------------------------
// Kernel 2: K[i][j] = exp(20*S - 20), S = sum_c min(ps[i,c], pt[j,c])  (fp16)
// 128x128 tile, 256 threads, 8x8 frags split +-64.
// amdgpu_waves_per_eu(1,1): grid=256 -> 1 wave/SIMD at runtime anyway; give
// the allocator the full unified register budget so acc[8][8] stays in arch
// VGPRs. Inline-asm pk_min+dot2 with "+v" pins the 2-instruction inner pair
// (round-1 counters showed 2.37x instr bloat = AGPR read/write wrapping).
// ---------------------------------------------------------------------------
__attribute__((amdgpu_waves_per_eu(1, 1)))
__global__ __launch_bounds__(256) void cdist_k(const _Float16* __restrict__ ps,
                                               const _Float16* __restrict__ pt,
                                               float* __restrict__ Km) {
    __shared__ __align__(16) v2h As[16][132];
    __shared__ __align__(16) v2h Bs[16][132];
    int tid = threadIdx.x;
    int tx = tid & 15, ty = tid >> 4;
    int r0 = blockIdx.y * 128, c0 = blockIdx.x * 128;

    float acc[8][8];
    #pragma unroll
    for (int i = 0; i < 8; ++i)
        #pragma unroll
        for (int j = 0; j < 8; ++j) acc[i][j] = 0.f;

    int lr = tid >> 1;
    int lq = tid & 1;
    const float4* pa = reinterpret_cast<const float4*>(ps + (size_t)(r0 + lr) * C);
    const float4* pb = reinterpret_cast<const float4*>(pt + (size_t)(c0 + lr) * C);
    const v2h one2 = {(_Float16)1.0f, (_Float16)1.0f};

    // prefetch ch=0
    float4 a0 = pa[lq * 2];
    float4 a1 = pa[lq * 2 + 1];
    float4 b0 = pb[lq * 2];
    float4 b1 = pb[lq * 2 + 1];

    for (int ch = 0; ch < 32; ++ch) {
        v2h* ah0 = (v2h*)&a0; v2h* ah1 = (v2h*)&a1;
        v2h* bh0 = (v2h*)&b0; v2h* bh1 = (v2h*)&b1;
        #pragma unroll
        for (int c2 = 0; c2 < 4; ++c2) {
            As[lq * 8 + c2][lr]     = ah0[c2];
            As[lq * 8 + 4 + c2][lr] = ah1[c2];
            Bs[lq * 8 + c2][lr]     = bh0[c2];
            Bs[lq * 8 + 4 + c2][lr] = bh1[c2];
        }
        __syncthreads();

        // issue next chunk's loads; latency hides under the 16-k2 compute
        int nch = (ch + 1) & 31;
        float4 na0 = pa[nch * 4 + lq * 2];
        float4 na1 = pa[nch * 4 + lq * 2 + 1];
        float4 nb0 = pb[nch * 4 + lq * 2];
        float4 nb1 = pb[nch * 4 + lq * 2 + 1];

        #pragma unroll
        for (int k2 = 0; k2 < 16; ++k2) {
            v2h a2[8], b2[8];
            *(float4*)&a2[0] = *(const float4*)&As[k2][ty * 4];
            *(float4*)&a2[4] = *(const float4*)&As[k2][64 + ty * 4];
            *(float4*)&b2[0] = *(const float4*)&Bs[k2][tx * 4];
            *(float4*)&b2[4] = *(const float4*)&Bs[k2][64 + tx * 4];
            #pragma unroll
            for (int i = 0; i < 8; ++i)
                #pragma unroll
                for (int j = 0; j < 8; ++j) {
                    v2h tmp;
                    asm("v_pk_min_f16 %1, %2, %3\n\t"
                        "v_dot2_f32_f16 %0, %1, %4, %0"
                        : "+v"(acc[i][j]), "=&v"(tmp)
                        : "v"(a2[i]), "v"(b2[j]), "v"(one2));
                }
        }
        __syncthreads();
        a0 = na0; a1 = na1; b0 = nb0; b1 = nb1;
    }

    #pragma unroll
    for (int i = 0; i < 8; ++i) {
        int row = r0 + ((i < 4) ? (ty * 4 + i) : (64 + ty * 4 + (i - 4)));
        float4 k0, k1;
        k0.x = __expf(20.f * acc[i][0] - 20.f);
        k0.y = __expf(20.f * acc[i][1] - 20.f);
        k0.z = __expf(20.f * acc[i][2] - 20.f);
        k0.w = __expf(20.f * acc[i][3] - 20.f);
        k1.x = __expf(20.f * acc[i][4] - 20.f);
        k1.y = __expf(20.f * acc[i][5] - 20.f);
        k1.z = __expf(20.f * acc[i][6] - 20.f);
        k1.w = __expf(20.f * acc[i][7] - 20.f);
        *reinterpret_cast<float4*>(&Km[(size_t)row * B + c0 + tx * 4]) = k0;
        *reinterpret_cast<float4*>(&Km[(size_t)row * B + c0 + 64 + tx * 4]) = k1;
    }
}

// ---------------------------------------------------------------------------
// Kernel 3: persistent Sinkhorn + loss. 256 blocks x 1024 threads (1 block/CU,
// all co-resident). Each block owns 8 rows; each thread owns 2 rotated cols.
// The whole K matrix lives in registers (kreg[8] float2/thread) for all 20
// iterations -- Km is read from global exactly once. Grid-wide sync via a
// flag-array barrier: parallel release-stores, block 0 aggregates, go
// broadcast (agent-scope acquire/release per G16 for cross-XCD coherence).
// ---------------------------------------------------------------------------
__global__ __launch_bounds__(1024, 4) void sink_k(const float* __restrict__ Km,
                                                  float* __restrict__ svec,
                                                  unsigned* __restrict__ flags,
                                                  float* __restrict__ out) {
    __shared__ float part[8][16];
    __shared__ float a_lds[8];
    __shared__ float lpart[16];
    int t0 = threadIdx.x;
    int lane = t0 & 63, wv = t0 >> 6;
    int bid = blockIdx.x;
    int r0 = bid * 8;
    int jx = (2 * t0 + 8 * bid) & (B - 1);   // even, 8B-aligned, rotated
    unsigned* go = flags + NBLK;

    float2 kreg[8];
    #pragma unroll
    for (int i = 0; i < 8; ++i)
        kreg[i] = *reinterpret_cast<const float2*>(&Km[(size_t)(r0 + i) * B + jx]);

    for (int t = 1; t <= 20; ++t) {
        float bx, by;
        if (t == 1) {
            bx = 1.0f; by = 1.0f;            // s0 == ones
        } else {
            float2 sv = *reinterpret_cast<const float2*>(&svec[(size_t)(t - 1) * B + jx]);
            bx = 1.0f / sv.x; by = 1.0f / sv.y;
        }

        // row sums: accr[i] = sum_j K_ij / s_j  (this thread's 2-col partial)
        float accr[8];
        #pragma unroll
        for (int i = 0; i < 8; ++i) accr[i] = kreg[i].x * bx + kreg[i].y * by;
        #pragma unroll
        for (int i = 0; i < 8; ++i) {
            float v = accr[i];
            #pragma unroll
            for (int m = 32; m >= 1; m >>= 1) v += __shfl_xor(v, m, 64);
            if (lane == 0) part[i][wv] = v;
        }
        __syncthreads();
        if (t0 < 8) {
            float s = 0.f;
            #pragma unroll
            for (int w = 0; w < 16; ++w) s += part[t0][w];
            a_lds[t0] = 1.0f / s;
        }
        __syncthreads();

        // column partials -> next scale vector
        float cx = 0.f, cy = 0.f;
        #pragma unroll
        for (int i = 0; i < 8; ++i) {
            float ai = a_lds[i];
            cx += ai * kreg[i].x;
            cy += ai * kreg[i].y;
        }
        float* snext = svec + (size_t)t * B;
        atomicAdd(&snext[jx], cx);
        atomicAdd(&snext[jx + 1], cy);

        // ---- grid barrier (flag array + go broadcast) ----
        __syncthreads();   // drains this block's atomics (vmcnt(0) at barrier)
        if (t0 == 0)
            __hip_atomic_store(&flags[bid], (unsigned)t,
                               __ATOMIC_RELEASE, __HIP_MEMORY_SCOPE_AGENT);
        if (bid == 0) {
            if (t0 < NBLK) {
                while (__hip_atomic_load(&flags[t0], __ATOMIC_ACQUIRE,
                                         __HIP_MEMORY_SCOPE_AGENT) < (unsigned)t)
                    __builtin_amdgcn_s_sleep(1);
            }
            __syncthreads();
            if (t0 == 0)
                __hip_atomic_store(go, (unsigned)t,
                                   __ATOMIC_RELEASE, __HIP_MEMORY_SCOPE_AGENT);
        }
        if (t0 == 0) {
            while (__hip_atomic_load(go, __ATOMIC_ACQUIRE,
                                     __HIP_MEMORY_SCOPE_AGENT) < (unsigned)t)
                __builtin_amdgcn_s_sleep(1);
        }
        __syncthreads();
    }

    // ---- fused loss: -1e-4 * sum_ij a_i K_ij (1/s20_j) ln K_ij ----
    const float* s20 = svec + (size_t)20 * B;
    float2 sv = *reinterpret_cast<const float2*>(&s20[jx]);
    float bx = 1.0f / sv.x, by = 1.0f / sv.y;
    float acc = 0.f;
    #pragma unroll
    for (int i = 0; i < 8; ++i) {
        float ai = a_lds[i];   // final a from iteration 20
        acc += ai * (kreg[i].x * bx * __logf(kreg[i].x) +
                     kreg[i].y * by * __logf(kreg[i].y));
    }
    #pragma unroll
    for (int m = 32; m >= 1; m >>= 1) acc += __shfl_xor(acc, m, 64);
    if (lane == 0) lpart[wv] = acc;
    __syncthreads();
    if (t0 == 0) {
        float s = 0.f;
        #pragma unroll
        for (int w = 0; w < 16; ++w) s += lpart[w];
        atomicAdd(out, -0.1f * 0.001f * s);
    }
}

// ---------------------------------------------------------------------------
extern "C" void kernel_launch(void* const* d_in, const int* in_sizes, int n_in,
                              void* d_out, int out_size, void* d_ws, size_t ws_size,
                              hipStream_t stream) {
    const float* ys = (const float*)d_in[0];
    const float* yt = (const float*)d_in[1];
    float* out = (float*)d_out;

    char* wsb = (char*)d_ws;
    _Float16* ps = (_Float16*)wsb;                               // 4 MB
    _Float16* pt = (_Float16*)(wsb + (size_t)B * C * 2);         // 4 MB
    float* Km    = (float*)(wsb + (size_t)2 * B * C * 2);        // 16.8 MB
    float* svec  = Km + (size_t)B * B;                           // 21*B floats
    unsigned* flags = (unsigned*)(svec + (size_t)21 * B);        // NBLK + 1

    (void)hipMemsetAsync(svec + B, 0, (size_t)20 * B * sizeof(float), stream);
    (void)hipMemsetAsync(flags, 0, (NBLK + 1) * sizeof(unsigned), stream);
    (void)hipMemsetAsync(out, 0, sizeof(float), stream);

    softmax_k<<<2 * B, 256, 0, stream>>>(ys, yt, ps, pt);
    cdist_k<<<dim3(16, 16), 256, 0, stream>>>(ps, pt, Km);
    sink_k<<<NBLK, 1024, 0, stream>>>(Km, svec, flags, out);
}